// Round 3
// baseline (223.445 us; speedup 1.0000x reference)
//
#include <hip/hip_runtime.h>
#include <math.h>

static constexpr int N_NODES = 50000;
static constexpr int N_EDGES = 800000;
static constexpr int NFEAT = 512;
static constexpr int NHID = 96;
static constexpr int NCLASS = 40;
static constexpr int SCAN_BLOCKS = (N_NODES + 255) / 256;  // 196

typedef __bf16 bf16_t;
typedef __attribute__((ext_vector_type(8))) __bf16 bf16x8;
typedef __attribute__((ext_vector_type(4))) float f32x4;

// ---------------------------------------------------------------------------
// Zero-fill (replaces hipMemsetAsync: rocclr fillBuffer ran at 3.4 GB/s, 58us)
// ---------------------------------------------------------------------------
__global__ __launch_bounds__(256) void k_zero(int* __restrict__ p, int n) {
    int i = blockIdx.x * 256 + threadIdx.x;
    if (i < n) p[i] = 0;
}

// ---------------------------------------------------------------------------
// One-time: W1 [512][96] f32  ->  W1t [96][512] bf16 (transpose + convert)
// ---------------------------------------------------------------------------
__global__ __launch_bounds__(256) void k_w1t(const float* __restrict__ W1,
                                             bf16_t* __restrict__ w1t) {
    int e = blockIdx.x * 256 + threadIdx.x;
    if (e < NFEAT * NHID) {
        int k = e / NHID;
        int n = e - k * NHID;
        w1t[(size_t)n * NFEAT + k] = (bf16_t)W1[e];
    }
}

// ---------------------------------------------------------------------------
// GEMM1 (bf16 MFMA): support[M,96] = x[M,512] @ W1[512,96] + b1
// Block = 64 rows, 4 waves; wave owns 16 rows x 96 cols (6 n-tiles of 16).
// ---------------------------------------------------------------------------
static __device__ inline bf16x8 cvt8(float4 u, float4 v) {
    bf16x8 r;
    r[0] = (bf16_t)u.x; r[1] = (bf16_t)u.y; r[2] = (bf16_t)u.z; r[3] = (bf16_t)u.w;
    r[4] = (bf16_t)v.x; r[5] = (bf16_t)v.y; r[6] = (bf16_t)v.z; r[7] = (bf16_t)v.w;
    return r;
}

__global__ __launch_bounds__(256) void k_gemm1_mfma(const float* __restrict__ x,
                                                    const bf16_t* __restrict__ w1t,
                                                    const float* __restrict__ b1,
                                                    float* __restrict__ support) {
    __shared__ bf16_t Bs[NHID * 64];  // [n][k] 96x64 bf16 = 12KB, XOR-swizzled
    const int tid = threadIdx.x;
    const int w = tid >> 6;
    const int l = tid & 63;
    const int row0 = blockIdx.x * 64;

    int arow = row0 + w * 16 + (l & 15);
    if (arow > N_NODES - 1) arow = N_NODES - 1;  // clamp: dup loads, masked store
    const float* ap = x + (size_t)arow * NFEAT + ((l >> 4) << 3);

    f32x4 acc[6];
#pragma unroll
    for (int nt = 0; nt < 6; ++nt) acc[nt] = (f32x4){0.f, 0.f, 0.f, 0.f};

    for (int kt = 0; kt < NFEAT; kt += 64) {
        // A loads for both K-steps of this tile (issued early, hide under staging)
        float4 a0 = *reinterpret_cast<const float4*>(ap + kt);
        float4 a1 = *reinterpret_cast<const float4*>(ap + kt + 4);
        float4 a2 = *reinterpret_cast<const float4*>(ap + kt + 32);
        float4 a3 = *reinterpret_cast<const float4*>(ap + kt + 36);

        __syncthreads();  // previous tile's B reads complete
        // stage B tile: 96 rows x 128B, swizzled writes (reg-staged, both sides XOR)
#pragma unroll
        for (int p = 0; p < 3; ++p) {
            int idx = tid + p * 256;      // 0..767
            int n = idx >> 3;             // 0..95
            int c = idx & 7;              // 16B chunk in row
            uint4 v = *reinterpret_cast<const uint4*>(w1t + (size_t)n * NFEAT + kt + c * 8);
            int ba = (n * 128 + c * 16) ^ ((n & 7) << 4);
            *reinterpret_cast<uint4*>(reinterpret_cast<char*>(Bs) + ba) = v;
        }
        __syncthreads();

        bf16x8 af0 = cvt8(a0, a1);
        bf16x8 af1 = cvt8(a2, a3);
        const int koff = (l >> 4) << 4;  // kblk*16 bytes
#pragma unroll
        for (int nt = 0; nt < 6; ++nt) {
            int n = nt * 16 + (l & 15);
            int ba0 = (n * 128 + koff) ^ ((n & 7) << 4);
            int ba1 = (n * 128 + 64 + koff) ^ ((n & 7) << 4);
            bf16x8 bf0 = *reinterpret_cast<const bf16x8*>(reinterpret_cast<const char*>(Bs) + ba0);
            bf16x8 bf1 = *reinterpret_cast<const bf16x8*>(reinterpret_cast<const char*>(Bs) + ba1);
            acc[nt] = __builtin_amdgcn_mfma_f32_16x16x32_bf16(af0, bf0, acc[nt], 0, 0, 0);
            acc[nt] = __builtin_amdgcn_mfma_f32_16x16x32_bf16(af1, bf1, acc[nt], 0, 0, 0);
        }
    }

    // Epilogue: C layout col=lane&15, row=(lane>>4)*4+reg (m89-verified mapping)
    const int col16 = l & 15;
    const int rq = l >> 4;
#pragma unroll
    for (int nt = 0; nt < 6; ++nt) {
        int col = nt * 16 + col16;
        float bv = b1[col];
#pragma unroll
        for (int r = 0; r < 4; ++r) {
            int row = row0 + w * 16 + rq * 4 + r;
            if (row < N_NODES)
                support[(size_t)row * NHID + col] = acc[nt][r] + bv;
        }
    }
}

// ---------------------------------------------------------------------------
// CSR build: histogram -> hierarchical scan (3 kernels) -> counting-sort scatter
// ---------------------------------------------------------------------------
__global__ __launch_bounds__(256) void k_hist(const int* __restrict__ dst,
                                              int* __restrict__ deg) {
    int i = blockIdx.x * 256 + threadIdx.x;
    if (i < N_EDGES) atomicAdd(&deg[dst[i]], 1);
}

__global__ __launch_bounds__(256) void k_scan1(const int* __restrict__ deg,
                                               int* __restrict__ row_ptr,
                                               int* __restrict__ blk_sum) {
    __shared__ int wsum[4];
    const int t = threadIdx.x;
    const int lane = t & 63, wid = t >> 6;
    const int i = blockIdx.x * 256 + t;
    int v = (i < N_NODES) ? deg[i] : 0;
    int xv = v;
#pragma unroll
    for (int off = 1; off < 64; off <<= 1) {
        int y = __shfl_up(xv, off);
        if (lane >= off) xv += y;
    }
    if (lane == 63) wsum[wid] = xv;
    __syncthreads();
    if (t == 0) {
        int s = 0;
#pragma unroll
        for (int j = 0; j < 4; ++j) { int tmp = wsum[j]; wsum[j] = s; s += tmp; }
        blk_sum[blockIdx.x] = s;
    }
    __syncthreads();
    if (i < N_NODES) row_ptr[i] = wsum[wid] + xv - v;  // block-local exclusive
}

__global__ __launch_bounds__(256) void k_scan2(const int* __restrict__ blk_sum,
                                               int* __restrict__ blk_off,
                                               int* __restrict__ row_ptr) {
    __shared__ int wsum[4];
    const int t = threadIdx.x;
    const int lane = t & 63, wid = t >> 6;
    int v = (t < SCAN_BLOCKS) ? blk_sum[t] : 0;
    int xv = v;
#pragma unroll
    for (int off = 1; off < 64; off <<= 1) {
        int y = __shfl_up(xv, off);
        if (lane >= off) xv += y;
    }
    if (lane == 63) wsum[wid] = xv;
    __syncthreads();
    if (t == 0) {
        int s = 0;
#pragma unroll
        for (int j = 0; j < 4; ++j) { int tmp = wsum[j]; wsum[j] = s; s += tmp; }
        row_ptr[N_NODES] = s;  // grand total (= N_EDGES)
    }
    __syncthreads();
    if (t < SCAN_BLOCKS) blk_off[t] = wsum[wid] + xv - v;
}

__global__ __launch_bounds__(256) void k_scan3(int* __restrict__ row_ptr,
                                               int* __restrict__ cursor,
                                               const int* __restrict__ blk_off) {
    int i = blockIdx.x * 256 + threadIdx.x;
    if (i < N_NODES) {
        int v = row_ptr[i] + blk_off[blockIdx.x];
        row_ptr[i] = v;
        cursor[i] = v;
    }
}

__global__ __launch_bounds__(256) void k_scatter(const int* __restrict__ src,
                                                 const int* __restrict__ dst,
                                                 const float* __restrict__ ew,
                                                 int* __restrict__ cursor,
                                                 int2* __restrict__ sorted) {
    int i = blockIdx.x * 256 + threadIdx.x;
    if (i < N_EDGES) {
        int d = dst[i];
        int pos = atomicAdd(&cursor[d], 1);
        sorted[pos] = make_int2(src[i], __float_as_int(ew[i]));
    }
}

// ---------------------------------------------------------------------------
// Pull-mode aggregate + ReLU. One 64-lane wave per node, TWO edges in flight:
// lanes 0-31 = edge e, lanes 32-63 = edge e+1 (halves the dependent-gather
// chain: avg-deg 16 -> 8 serial iters per half). Final __shfl_xor(32) reduce.
// ---------------------------------------------------------------------------
__global__ __launch_bounds__(256) void k_agg(const float* __restrict__ support,
                                             const int* __restrict__ row_ptr,
                                             const int2* __restrict__ sorted,
                                             float* __restrict__ h) {
    const int g = blockIdx.x * 4 + (threadIdx.x >> 6);
    if (g >= N_NODES) return;
    const int l = threadIdx.x & 63;
    const int half = l >> 5;
    const int li = l & 31;
    const int beg = row_ptr[g];
    const int end = row_ptr[g + 1];
    float a0 = 0.f, a1 = 0.f, a2 = 0.f;
    for (int e = beg + half; e < end; e += 2) {
        int2 s = sorted[e];
        const float* r = support + (size_t)s.x * NHID;
        float wv = __int_as_float(s.y);
        a0 = fmaf(wv, r[li], a0);
        a1 = fmaf(wv, r[li + 32], a1);
        a2 = fmaf(wv, r[li + 64], a2);
    }
    a0 += __shfl_xor(a0, 32);
    a1 += __shfl_xor(a1, 32);
    a2 += __shfl_xor(a2, 32);
    if (half == 0) {
        float* hr = h + (size_t)g * NHID;
        hr[li] = fmaxf(a0, 0.f);
        hr[li + 32] = fmaxf(a1, 0.f);
        hr[li + 64] = fmaxf(a2, 0.f);
    }
}

// ---------------------------------------------------------------------------
// Fallback (small workspace): atomic scatter-add aggregate, then ReLU.
// ---------------------------------------------------------------------------
__global__ __launch_bounds__(256) void k_agg_atomic(const float* __restrict__ support,
                                                    const int* __restrict__ src,
                                                    const int* __restrict__ dst,
                                                    const float* __restrict__ ew,
                                                    float* __restrict__ h) {
    int e = blockIdx.x * 8 + (threadIdx.x >> 5);
    int l = threadIdx.x & 31;
    if (e >= N_EDGES) return;
    int s = src[e];
    int d = dst[e];
    float w = ew[e];
    const float* r = support + (size_t)s * NHID;
    float* hd = h + (size_t)d * NHID;
    atomicAdd(&hd[l], w * r[l]);
    atomicAdd(&hd[l + 32], w * r[l + 32]);
    atomicAdd(&hd[l + 64], w * r[l + 64]);
}

__global__ __launch_bounds__(256) void k_relu(float* __restrict__ h) {
    int i = blockIdx.x * 256 + threadIdx.x;
    if (i < N_NODES * NHID) h[i] = fmaxf(h[i], 0.f);
}

// ---------------------------------------------------------------------------
// GEMM2 + bias + log_softmax fused. One row per wave per iter; lanes 0..39 = classes.
// ---------------------------------------------------------------------------
__global__ __launch_bounds__(256) void k_gemm2(const float* __restrict__ h,
                                               const float* __restrict__ W2,
                                               const float* __restrict__ b2,
                                               float* __restrict__ out) {
    __shared__ float w2s[NHID * NCLASS + 64];  // +64 pad: lanes 40..63 read junk, masked
    __shared__ float b2s[NCLASS];
    __shared__ float hb[4][NHID];
    const int tid = threadIdx.x;
    for (int i = tid; i < NHID * NCLASS; i += 256) w2s[i] = W2[i];
    if (tid < NCLASS) b2s[tid] = b2[tid];
    const int wid = tid >> 6;
    const int lane = tid & 63;

    for (int rbase = blockIdx.x * 4; rbase < N_NODES; rbase += gridDim.x * 4) {
        __syncthreads();
        for (int i = tid; i < 4 * NHID; i += 256) {
            int r = i / NHID, c = i - r * NHID;
            int row = rbase + r;
            hb[r][c] = (row < N_NODES) ? h[(size_t)row * NHID + c] : 0.f;
        }
        __syncthreads();
        const int row = rbase + wid;
        float acc = (lane < NCLASS) ? b2s[lane] : 0.f;
#pragma unroll 8
        for (int k = 0; k < NHID; ++k)
            acc = fmaf(hb[wid][k], w2s[k * NCLASS + lane], acc);
        float m = (lane < NCLASS) ? acc : -1e30f;
#pragma unroll
        for (int off = 32; off > 0; off >>= 1) m = fmaxf(m, __shfl_xor(m, off));
        float ev = (lane < NCLASS) ? __expf(acc - m) : 0.f;
        float s = ev;
#pragma unroll
        for (int off = 32; off > 0; off >>= 1) s += __shfl_xor(s, off);
        if (row < N_NODES && lane < NCLASS)
            out[(size_t)row * NCLASS + lane] = acc - m - __logf(s);
    }
}

// ---------------------------------------------------------------------------
extern "C" void kernel_launch(void* const* d_in, const int* in_sizes, int n_in,
                              void* d_out, int out_size, void* d_ws, size_t ws_size,
                              hipStream_t stream) {
    const float* x  = (const float*)d_in[0];
    const int* ei   = (const int*)d_in[1];
    const float* ew = (const float*)d_in[2];
    const float* W1 = (const float*)d_in[3];
    const float* b1 = (const float*)d_in[4];
    const float* W2 = (const float*)d_in[5];
    const float* b2 = (const float*)d_in[6];
    float* out = (float*)d_out;
    const int* src = ei;
    const int* dst = ei + N_EDGES;

    char* ws = (char*)d_ws;
    size_t off = 0;
    auto alloc = [&](size_t bytes) -> void* {
        void* p = ws + off;
        off = (off + bytes + 255) & ~(size_t)255;
        return p;
    };
    float* support = (float*)alloc((size_t)N_NODES * NHID * 4);
    float* h       = (float*)alloc((size_t)N_NODES * NHID * 4);
    bf16_t* w1t    = (bf16_t*)alloc((size_t)NHID * NFEAT * 2);
    int* deg       = (int*)alloc((size_t)N_NODES * 4);
    int* row_ptr   = (int*)alloc((size_t)(N_NODES + 1) * 4);
    int* cursor    = (int*)alloc((size_t)N_NODES * 4);
    int* blk_sum   = (int*)alloc(256 * 4);
    int* blk_off   = (int*)alloc(256 * 4);
    int2* sorted   = (int2*)alloc((size_t)N_EDGES * 8);
    const bool csr_fits = (off <= ws_size);

    k_w1t<<<(NFEAT * NHID + 255) / 256, 256, 0, stream>>>(W1, w1t);
    k_gemm1_mfma<<<(N_NODES + 63) / 64, 256, 0, stream>>>(x, w1t, b1, support);

    if (csr_fits) {
        k_zero<<<SCAN_BLOCKS, 256, 0, stream>>>(deg, N_NODES);
        k_hist<<<(N_EDGES + 255) / 256, 256, 0, stream>>>(dst, deg);
        k_scan1<<<SCAN_BLOCKS, 256, 0, stream>>>(deg, row_ptr, blk_sum);
        k_scan2<<<1, 256, 0, stream>>>(blk_sum, blk_off, row_ptr);
        k_scan3<<<SCAN_BLOCKS, 256, 0, stream>>>(row_ptr, cursor, blk_off);
        k_scatter<<<(N_EDGES + 255) / 256, 256, 0, stream>>>(src, dst, ew, cursor, sorted);
        k_agg<<<(N_NODES + 3) / 4, 256, 0, stream>>>(support, row_ptr, sorted, h);
    } else {
        k_zero<<<(N_NODES * NHID + 255) / 256, 256, 0, stream>>>((int*)h, N_NODES * NHID);
        k_agg_atomic<<<(N_EDGES + 7) / 8, 256, 0, stream>>>(support, src, dst, ew, h);
        k_relu<<<(N_NODES * NHID + 255) / 256, 256, 0, stream>>>(h);
    }

    k_gemm2<<<3125, 256, 0, stream>>>(h, W2, b2, out);
}

// Round 4
// 162.558 us; speedup vs baseline: 1.3746x; 1.3746x over previous
//
#include <hip/hip_runtime.h>
#include <math.h>

static constexpr int N_NODES = 50000;
static constexpr int N_EDGES = 800000;
static constexpr int NFEAT = 512;
static constexpr int NHID = 96;
static constexpr int NCLASS = 40;
static constexpr int SCAN_BLOCKS = (N_NODES + 255) / 256;  // 196
static constexpr int W2LD = 104;  // padded row stride for W2t (bank-friendly)

typedef __bf16 bf16_t;
typedef __attribute__((ext_vector_type(8))) __bf16 bf16x8;
typedef __attribute__((ext_vector_type(4))) float f32x4;

// ---------------------------------------------------------------------------
// Zero-fill
// ---------------------------------------------------------------------------
__global__ __launch_bounds__(256) void k_zero(int* __restrict__ p, int n) {
    int i = blockIdx.x * 256 + threadIdx.x;
    if (i < n) p[i] = 0;
}

// ---------------------------------------------------------------------------
// Prep: W1 [512][96] f32 -> w1t [96][512] bf16; W2 [96][40] f32 -> w2t [48][96]
// bf16 (transposed, zero-padded cols 40..47, row stride W2LD).
// ---------------------------------------------------------------------------
__global__ __launch_bounds__(256) void k_prep(const float* __restrict__ W1,
                                              const float* __restrict__ W2,
                                              bf16_t* __restrict__ w1t,
                                              bf16_t* __restrict__ w2t) {
    int e = blockIdx.x * 256 + threadIdx.x;
    if (e < NFEAT * NHID) {
        int k = e / NHID;
        int n = e - k * NHID;
        w1t[(size_t)n * NFEAT + k] = (bf16_t)W1[e];
    }
    if (e < 48 * NHID) {
        int n = e / NHID;
        int k = e - n * NHID;
        w2t[n * W2LD + k] = (n < NCLASS) ? (bf16_t)W2[k * NCLASS + n] : (bf16_t)0.f;
    }
}

// ---------------------------------------------------------------------------
// GEMM1 (bf16 MFMA): support[M,96](bf16) = x[M,512] @ W1[512,96] + b1
// ---------------------------------------------------------------------------
static __device__ inline bf16x8 cvt8(float4 u, float4 v) {
    bf16x8 r;
    r[0] = (bf16_t)u.x; r[1] = (bf16_t)u.y; r[2] = (bf16_t)u.z; r[3] = (bf16_t)u.w;
    r[4] = (bf16_t)v.x; r[5] = (bf16_t)v.y; r[6] = (bf16_t)v.z; r[7] = (bf16_t)v.w;
    return r;
}

__global__ __launch_bounds__(256) void k_gemm1_mfma(const float* __restrict__ x,
                                                    const bf16_t* __restrict__ w1t,
                                                    const float* __restrict__ b1,
                                                    bf16_t* __restrict__ support) {
    __shared__ bf16_t Bs[NHID * 64];  // [n][k] 96x64 bf16 = 12KB, XOR-swizzled
    const int tid = threadIdx.x;
    const int w = tid >> 6;
    const int l = tid & 63;
    const int row0 = blockIdx.x * 64;

    int arow = row0 + w * 16 + (l & 15);
    if (arow > N_NODES - 1) arow = N_NODES - 1;  // clamp: dup loads, masked store
    const float* ap = x + (size_t)arow * NFEAT + ((l >> 4) << 3);

    f32x4 acc[6];
#pragma unroll
    for (int nt = 0; nt < 6; ++nt) acc[nt] = (f32x4){0.f, 0.f, 0.f, 0.f};

    for (int kt = 0; kt < NFEAT; kt += 64) {
        float4 a0 = *reinterpret_cast<const float4*>(ap + kt);
        float4 a1 = *reinterpret_cast<const float4*>(ap + kt + 4);
        float4 a2 = *reinterpret_cast<const float4*>(ap + kt + 32);
        float4 a3 = *reinterpret_cast<const float4*>(ap + kt + 36);

        __syncthreads();
#pragma unroll
        for (int p = 0; p < 3; ++p) {
            int idx = tid + p * 256;
            int n = idx >> 3;
            int c = idx & 7;
            uint4 v = *reinterpret_cast<const uint4*>(w1t + (size_t)n * NFEAT + kt + c * 8);
            int ba = (n * 128 + c * 16) ^ ((n & 7) << 4);
            *reinterpret_cast<uint4*>(reinterpret_cast<char*>(Bs) + ba) = v;
        }
        __syncthreads();

        bf16x8 af0 = cvt8(a0, a1);
        bf16x8 af1 = cvt8(a2, a3);
        const int koff = (l >> 4) << 4;
#pragma unroll
        for (int nt = 0; nt < 6; ++nt) {
            int n = nt * 16 + (l & 15);
            int ba0 = (n * 128 + koff) ^ ((n & 7) << 4);
            int ba1 = (n * 128 + 64 + koff) ^ ((n & 7) << 4);
            bf16x8 bf0 = *reinterpret_cast<const bf16x8*>(reinterpret_cast<const char*>(Bs) + ba0);
            bf16x8 bf1 = *reinterpret_cast<const bf16x8*>(reinterpret_cast<const char*>(Bs) + ba1);
            acc[nt] = __builtin_amdgcn_mfma_f32_16x16x32_bf16(af0, bf0, acc[nt], 0, 0, 0);
            acc[nt] = __builtin_amdgcn_mfma_f32_16x16x32_bf16(af1, bf1, acc[nt], 0, 0, 0);
        }
    }

    const int col16 = l & 15;
    const int rq = l >> 4;
#pragma unroll
    for (int nt = 0; nt < 6; ++nt) {
        int col = nt * 16 + col16;
        float bv = b1[col];
#pragma unroll
        for (int r = 0; r < 4; ++r) {
            int row = row0 + w * 16 + rq * 4 + r;
            if (row < N_NODES)
                support[(size_t)row * NHID + col] = (bf16_t)(acc[nt][r] + bv);
        }
    }
}

// ---------------------------------------------------------------------------
// CSR build: histogram -> hierarchical scan -> counting-sort scatter
// ---------------------------------------------------------------------------
__global__ __launch_bounds__(256) void k_hist(const int* __restrict__ dst,
                                              int* __restrict__ deg) {
    int i = blockIdx.x * 256 + threadIdx.x;
    if (i < N_EDGES) atomicAdd(&deg[dst[i]], 1);
}

__global__ __launch_bounds__(256) void k_scan1(const int* __restrict__ deg,
                                               int* __restrict__ row_ptr,
                                               int* __restrict__ blk_sum) {
    __shared__ int wsum[4];
    const int t = threadIdx.x;
    const int lane = t & 63, wid = t >> 6;
    const int i = blockIdx.x * 256 + t;
    int v = (i < N_NODES) ? deg[i] : 0;
    int xv = v;
#pragma unroll
    for (int off = 1; off < 64; off <<= 1) {
        int y = __shfl_up(xv, off);
        if (lane >= off) xv += y;
    }
    if (lane == 63) wsum[wid] = xv;
    __syncthreads();
    if (t == 0) {
        int s = 0;
#pragma unroll
        for (int j = 0; j < 4; ++j) { int tmp = wsum[j]; wsum[j] = s; s += tmp; }
        blk_sum[blockIdx.x] = s;
    }
    __syncthreads();
    if (i < N_NODES) row_ptr[i] = wsum[wid] + xv - v;
}

__global__ __launch_bounds__(256) void k_scan2(const int* __restrict__ blk_sum,
                                               int* __restrict__ blk_off,
                                               int* __restrict__ row_ptr) {
    __shared__ int wsum[4];
    const int t = threadIdx.x;
    const int lane = t & 63, wid = t >> 6;
    int v = (t < SCAN_BLOCKS) ? blk_sum[t] : 0;
    int xv = v;
#pragma unroll
    for (int off = 1; off < 64; off <<= 1) {
        int y = __shfl_up(xv, off);
        if (lane >= off) xv += y;
    }
    if (lane == 63) wsum[wid] = xv;
    __syncthreads();
    if (t == 0) {
        int s = 0;
#pragma unroll
        for (int j = 0; j < 4; ++j) { int tmp = wsum[j]; wsum[j] = s; s += tmp; }
        row_ptr[N_NODES] = s;
    }
    __syncthreads();
    if (t < SCAN_BLOCKS) blk_off[t] = wsum[wid] + xv - v;
}

__global__ __launch_bounds__(256) void k_scan3(int* __restrict__ row_ptr,
                                               int* __restrict__ cursor,
                                               const int* __restrict__ blk_off) {
    int i = blockIdx.x * 256 + threadIdx.x;
    if (i < N_NODES) {
        int v = row_ptr[i] + blk_off[blockIdx.x];
        row_ptr[i] = v;
        cursor[i] = v;
    }
}

__global__ __launch_bounds__(256) void k_scatter(const int* __restrict__ src,
                                                 const int* __restrict__ dst,
                                                 const float* __restrict__ ew,
                                                 int* __restrict__ cursor,
                                                 int2* __restrict__ sorted) {
    int i = blockIdx.x * 256 + threadIdx.x;
    if (i < N_EDGES) {
        int d = dst[i];
        int pos = atomicAdd(&cursor[d], 1);
        sorted[pos] = make_int2(src[i], __float_as_int(ew[i]));
    }
}

// ---------------------------------------------------------------------------
// Pull-mode aggregate + ReLU, bf16 support -> bf16 h.
// One 32-lane group per node; 4-edge unroll = 12 gathers in flight (MLP).
// ---------------------------------------------------------------------------
__global__ __launch_bounds__(256) void k_agg(const bf16_t* __restrict__ support,
                                             const int* __restrict__ row_ptr,
                                             const int2* __restrict__ sorted,
                                             bf16_t* __restrict__ h) {
    const int g = blockIdx.x * 8 + (threadIdx.x >> 5);
    const int l = threadIdx.x & 31;
    if (g >= N_NODES) return;
    const int beg = row_ptr[g];
    const int end = row_ptr[g + 1];
    float a0 = 0.f, a1 = 0.f, a2 = 0.f;
    int e = beg;
    for (; e + 4 <= end; e += 4) {
        int2 s0 = sorted[e];
        int2 s1 = sorted[e + 1];
        int2 s2 = sorted[e + 2];
        int2 s3 = sorted[e + 3];
        const bf16_t* r0 = support + (size_t)s0.x * NHID;
        const bf16_t* r1 = support + (size_t)s1.x * NHID;
        const bf16_t* r2 = support + (size_t)s2.x * NHID;
        const bf16_t* r3 = support + (size_t)s3.x * NHID;
        float w0 = __int_as_float(s0.y), w1 = __int_as_float(s1.y);
        float w2 = __int_as_float(s2.y), w3 = __int_as_float(s3.y);
        // all 12 gathers issued before the FMA block -> deep MLP
        float v00 = (float)r0[l], v01 = (float)r0[l + 32], v02 = (float)r0[l + 64];
        float v10 = (float)r1[l], v11 = (float)r1[l + 32], v12 = (float)r1[l + 64];
        float v20 = (float)r2[l], v21 = (float)r2[l + 32], v22 = (float)r2[l + 64];
        float v30 = (float)r3[l], v31 = (float)r3[l + 32], v32 = (float)r3[l + 64];
        a0 = fmaf(w0, v00, a0); a1 = fmaf(w0, v01, a1); a2 = fmaf(w0, v02, a2);
        a0 = fmaf(w1, v10, a0); a1 = fmaf(w1, v11, a1); a2 = fmaf(w1, v12, a2);
        a0 = fmaf(w2, v20, a0); a1 = fmaf(w2, v21, a1); a2 = fmaf(w2, v22, a2);
        a0 = fmaf(w3, v30, a0); a1 = fmaf(w3, v31, a1); a2 = fmaf(w3, v32, a2);
    }
    for (; e < end; ++e) {
        int2 s = sorted[e];
        const bf16_t* r = support + (size_t)s.x * NHID;
        float wv = __int_as_float(s.y);
        a0 = fmaf(wv, (float)r[l], a0);
        a1 = fmaf(wv, (float)r[l + 32], a1);
        a2 = fmaf(wv, (float)r[l + 64], a2);
    }
    bf16_t* hr = h + (size_t)g * NHID;
    hr[l]      = (bf16_t)fmaxf(a0, 0.f);
    hr[l + 32] = (bf16_t)fmaxf(a1, 0.f);
    hr[l + 64] = (bf16_t)fmaxf(a2, 0.f);
}

// ---------------------------------------------------------------------------
// Fallback (no CSR space): f32 atomics into hf, then ReLU+convert to bf16 h.
// ---------------------------------------------------------------------------
__global__ __launch_bounds__(256) void k_agg_atomic(const bf16_t* __restrict__ support,
                                                    const int* __restrict__ src,
                                                    const int* __restrict__ dst,
                                                    const float* __restrict__ ew,
                                                    float* __restrict__ hf) {
    int e = blockIdx.x * 8 + (threadIdx.x >> 5);
    int l = threadIdx.x & 31;
    if (e >= N_EDGES) return;
    int s = src[e];
    int d = dst[e];
    float w = ew[e];
    const bf16_t* r = support + (size_t)s * NHID;
    float* hd = hf + (size_t)d * NHID;
    atomicAdd(&hd[l], w * (float)r[l]);
    atomicAdd(&hd[l + 32], w * (float)r[l + 32]);
    atomicAdd(&hd[l + 64], w * (float)r[l + 64]);
}

__global__ __launch_bounds__(256) void k_relu_cvt(const float* __restrict__ hf,
                                                  bf16_t* __restrict__ h) {
    int i = blockIdx.x * 256 + threadIdx.x;
    if (i < N_NODES * NHID) h[i] = (bf16_t)fmaxf(hf[i], 0.f);
}

// ---------------------------------------------------------------------------
// GEMM2 (bf16 MFMA) + bias + log_softmax fused.
// Block = 64 rows (4 waves x 16); K=96 in 3 MFMA k-steps; N=40 in 3 n-tiles
// (cols 40..47 zero-padded). W2t staged once in LDS. Softmax: per C-layout
// row = 16-lane group x 3 regs; __shfl_xor(1,2,4,8) reduction.
// ---------------------------------------------------------------------------
__global__ __launch_bounds__(256) void k_gemm2_mfma(const bf16_t* __restrict__ h,
                                                    const bf16_t* __restrict__ w2t,
                                                    const float* __restrict__ b2,
                                                    float* __restrict__ out) {
    __shared__ bf16_t Bs[48 * W2LD];
    const int tid = threadIdx.x;
#pragma unroll
    for (int i = tid; i < 48 * W2LD / 8; i += 256)
        *reinterpret_cast<uint4*>(Bs + i * 8) =
            *reinterpret_cast<const uint4*>(w2t + i * 8);

    const int w = tid >> 6;
    const int l = tid & 63;
    const int row0 = blockIdx.x * 64 + w * 16;
    int arow = row0 + (l & 15);
    if (arow > N_NODES - 1) arow = N_NODES - 1;
    const bf16_t* ap = h + (size_t)arow * NHID + ((l >> 4) << 3);

    f32x4 acc[3];
#pragma unroll
    for (int nt = 0; nt < 3; ++nt) acc[nt] = (f32x4){0.f, 0.f, 0.f, 0.f};
    __syncthreads();

#pragma unroll
    for (int ks = 0; ks < 3; ++ks) {
        bf16x8 af = *reinterpret_cast<const bf16x8*>(ap + ks * 32);
#pragma unroll
        for (int nt = 0; nt < 3; ++nt) {
            int n = nt * 16 + (l & 15);
            bf16x8 bf = *reinterpret_cast<const bf16x8*>(
                &Bs[n * W2LD + ks * 32 + ((l >> 4) << 3)]);
            acc[nt] = __builtin_amdgcn_mfma_f32_16x16x32_bf16(af, bf, acc[nt], 0, 0, 0);
        }
    }

    const int c16 = l & 15;
    float bv[3];
    bool val[3];
#pragma unroll
    for (int nt = 0; nt < 3; ++nt) {
        int col = nt * 16 + c16;
        val[nt] = col < NCLASS;
        bv[nt] = val[nt] ? b2[col] : 0.f;
    }
#pragma unroll
    for (int r = 0; r < 4; ++r) {
        float lg[3];
        float m = -1e30f;
#pragma unroll
        for (int nt = 0; nt < 3; ++nt) {
            lg[nt] = acc[nt][r] + bv[nt];
            if (val[nt]) m = fmaxf(m, lg[nt]);
        }
#pragma unroll
        for (int off = 1; off < 16; off <<= 1) m = fmaxf(m, __shfl_xor(m, off));
        float s = 0.f;
#pragma unroll
        for (int nt = 0; nt < 3; ++nt)
            if (val[nt]) s += __expf(lg[nt] - m);
#pragma unroll
        for (int off = 1; off < 16; off <<= 1) s += __shfl_xor(s, off);
        float lse = __logf(s);
        int row = row0 + ((l >> 4) << 2) + r;
        if (row < N_NODES) {
#pragma unroll
            for (int nt = 0; nt < 3; ++nt)
                if (val[nt])
                    out[(size_t)row * NCLASS + nt * 16 + c16] = lg[nt] - m - lse;
        }
    }
}

// ---------------------------------------------------------------------------
extern "C" void kernel_launch(void* const* d_in, const int* in_sizes, int n_in,
                              void* d_out, int out_size, void* d_ws, size_t ws_size,
                              hipStream_t stream) {
    const float* x  = (const float*)d_in[0];
    const int* ei   = (const int*)d_in[1];
    const float* ew = (const float*)d_in[2];
    const float* W1 = (const float*)d_in[3];
    const float* b1 = (const float*)d_in[4];
    const float* W2 = (const float*)d_in[5];
    const float* b2 = (const float*)d_in[6];
    float* out = (float*)d_out;
    const int* src = ei;
    const int* dst = ei + N_EDGES;

    char* ws = (char*)d_ws;
    size_t off = 0;
    auto alloc = [&](size_t bytes) -> void* {
        void* p = ws + off;
        off = (off + bytes + 255) & ~(size_t)255;
        return p;
    };
    bf16_t* support = (bf16_t*)alloc((size_t)N_NODES * NHID * 2);
    bf16_t* h       = (bf16_t*)alloc((size_t)N_NODES * NHID * 2);
    bf16_t* w1t     = (bf16_t*)alloc((size_t)NHID * NFEAT * 2);
    bf16_t* w2t     = (bf16_t*)alloc((size_t)48 * W2LD * 2);
    int* deg        = (int*)alloc((size_t)N_NODES * 4);
    int* row_ptr    = (int*)alloc((size_t)(N_NODES + 1) * 4);
    int* cursor     = (int*)alloc((size_t)N_NODES * 4);
    int* blk_sum    = (int*)alloc(256 * 4);
    int* blk_off    = (int*)alloc(256 * 4);
    int2* sorted    = (int2*)alloc((size_t)N_EDGES * 8);
    const bool csr_fits = (off <= ws_size);
    float* hf       = (float*)alloc((size_t)N_NODES * NHID * 4);  // fallback only

    k_prep<<<(NFEAT * NHID + 255) / 256, 256, 0, stream>>>(W1, W2, w1t, w2t);
    k_gemm1_mfma<<<(N_NODES + 63) / 64, 256, 0, stream>>>(x, w1t, b1, support);

    if (csr_fits) {
        k_zero<<<SCAN_BLOCKS, 256, 0, stream>>>(deg, N_NODES);
        k_hist<<<(N_EDGES + 255) / 256, 256, 0, stream>>>(dst, deg);
        k_scan1<<<SCAN_BLOCKS, 256, 0, stream>>>(deg, row_ptr, blk_sum);
        k_scan2<<<1, 256, 0, stream>>>(blk_sum, blk_off, row_ptr);
        k_scan3<<<SCAN_BLOCKS, 256, 0, stream>>>(row_ptr, cursor, blk_off);
        k_scatter<<<(N_EDGES + 255) / 256, 256, 0, stream>>>(src, dst, ew, cursor, sorted);
        k_agg<<<(N_NODES + 7) / 8, 256, 0, stream>>>(support, row_ptr, sorted, h);
    } else {
        k_zero<<<(N_NODES * NHID + 255) / 256, 256, 0, stream>>>((int*)hf, N_NODES * NHID);
        k_agg_atomic<<<(N_EDGES + 7) / 8, 256, 0, stream>>>(support, src, dst, ew, hf);
        k_relu_cvt<<<(N_NODES * NHID + 255) / 256, 256, 0, stream>>>(hf, h);
    }

    k_gemm2_mfma<<<(N_NODES + 63) / 64, 256, 0, stream>>>(h, w2t, b2, out);
}